// Round 21
// baseline (119.263 us; speedup 1.0000x reference)
//
#include <hip/hip_runtime.h>

#define NNODES 100000
#define EDGES  262144
#define NT64   1563          // ceil(NNODES/64); last tile is half (guarded)
#define GEMM_BLOCKS 256

typedef __attribute__((ext_vector_type(8))) short short8v;
typedef __attribute__((ext_vector_type(8))) unsigned short ushort8v;
typedef __attribute__((ext_vector_type(4))) float f32x4;

__device__ __forceinline__ unsigned short f2bf(float f) {
  unsigned u = __builtin_bit_cast(unsigned, f);
  u += 0x7fffu + ((u >> 16) & 1u);
  return (unsigned short)(u >> 16);
}
__device__ __forceinline__ float bf2f(unsigned short u) {
  return __builtin_bit_cast(float, (unsigned)u << 16);
}
// HW packed f32->bf16 (RNE), two values -> one dword [lo|hi]
__device__ __forceinline__ unsigned cvt_pk(float lo, float hi) {
  unsigned r;
  asm volatile("v_cvt_pk_bf16_f32 %0, %1, %2" : "=v"(r) : "v"(lo), "v"(hi));
  return r;
}

// ---------------------------------------------------------------------------
// Kernel 0: repack W1 (fp32 [256][512]) -> Wc2 in WAVE-FRAGMENT order:
// Wc2[wid'][ks][jt'][lane][8] ushorts (256 KB); j = wid'*64 + jt'*16 + (lane&15),
// k = ks*32 + (lane>>4)*8 + m; value = W1[j&255][k + (k>=128?128:0) + (j>=256?128:0)].
// One bfrag = one contiguous 1 KB wave-load (proven r19).
// ---------------------------------------------------------------------------
__global__ __launch_bounds__(256) void prep_wc2(const float* __restrict__ W1,
                                                unsigned short* __restrict__ Wc2) {
  int idx  = blockIdx.x * 256 + threadIdx.x;   // 0 .. 131071
  int m    = idx & 7;
  int lane = (idx >> 3) & 63;
  int jt   = (idx >> 9) & 3;
  int ks   = (idx >> 11) & 7;
  int wid  = idx >> 14;                        // 0..7
  int j = wid * 64 + jt * 16 + (lane & 15);
  int k = ks * 32 + (lane >> 4) * 8 + m;
  int jj = j & 255;
  int kk = k + (k >= 128 ? 128 : 0) + (j >= 256 ? 128 : 0);
  Wc2[idx] = f2bf(W1[jj * 512 + kk]);
}

// ---------------------------------------------------------------------------
// GEMM v21: 512 thr = 8 waves; 64-NODE tiles; per tile an in-block j-half
// loop (#pragma unroll 1).  Per pass a wave owns 32 j: bfrag[8][2]=32 regs
// loaded INSIDE the pass as coalesced 1KB wave-loads (resident, no remat),
// acc[2][4]=32, g[8]=32 -> live-through ~116 < the 512-thr 128-reg budget.
// A-tile staged ONCE per tile (fixes r17's double-stage); rolled jh-loop
// avoids r16's co-live/forced-remat failure.  B traffic per node HALVES vs
// r19 (~425 MB L2); barriers halve (6-7/block).  LDS dbuf 2x64x272=69.6 KB.
//
// Wave wid, half jh covers j in [jh*256 + wid*32, +32):
//   wid' = jh*4 + (wid>>1), jt' = (wid&1)*2 + t   (t = 0,1) in Wc2 layout.
// P[n][j] = sum_k h[n][k]*Wc[j][k] + (j<256 ? b1[j] : 0)
// Swapped-operand MFMA: C row = j, col = node -> packed uint2 stores.
// ---------------------------------------------------------------------------
__global__ __launch_bounds__(512)
void gemm_proj21(const float* __restrict__ ne,
                 const float* __restrict__ mem,
                 const unsigned short* __restrict__ Wc2,
                 const float* __restrict__ b1,
                 unsigned short* __restrict__ P) {
  __shared__ __align__(16) unsigned short As[2][64][272];  // stride 272: 0 conflicts
  const int tid  = threadIdx.x;
  const int bid  = blockIdx.x;
  const int wid  = tid >> 6;          // 0..7
  const int lane = tid & 63;
  const int lr   = lane & 15;
  const int kq   = (lane >> 4) * 8;   // 0,8,16,24
  const int wsub = wid >> 1;          // 0..3
  const int jtb  = (wid & 1) * 2;     // 0 or 2

  const int nt = (NT64 - bid + GEMM_BLOCKS - 1) / GEMM_BLOCKS;  // 7 or 6

  // ---- stage tile 0 (4096 float4-chunks / 512 thr -> g[8]) ----
  float4 g[8];
#pragma unroll
  for (int i = 0; i < 8; ++i) {
    int q = tid + i * 512;            // 0..4095
    int row = q >> 6;                 // 0..63
    int k0  = (q & 63) * 4;
    int node = bid * 64 + row;        // bid<=255 -> node <= 16383, in range
    g[i] = *(const float4*)((k0 < 128) ? ne + (size_t)node * 128 + k0
                                       : mem + (size_t)node * 128 + (k0 - 128));
  }
#pragma unroll
  for (int i = 0; i < 8; ++i) {
    int q = tid + i * 512;
    int row = q >> 6;
    int k0  = (q & 63) * 4;
    uint2 pk { cvt_pk(g[i].x, g[i].y), cvt_pk(g[i].z, g[i].w) };
    *(uint2*)&As[0][row][k0] = pk;
  }
  __syncthreads();

  for (int it = 0; it < nt; ++it) {
    const int tile = bid + it * GEMM_BLOCKS;
    const int buf  = it & 1;
    const bool more = (it + 1 < nt);

    // issue next tile's global loads EARLY (clamped for the half tail-tile)
    if (more) {
      const int ntile = tile + GEMM_BLOCKS;
#pragma unroll
      for (int i = 0; i < 8; ++i) {
        int q = tid + i * 512;
        int row = q >> 6;
        int k0  = (q & 63) * 4;
        int node = ntile * 64 + row;
        if (node > NNODES - 1) node = NNODES - 1;   // clamp (load-safe)
        g[i] = *(const float4*)((k0 < 128) ? ne + (size_t)node * 128 + k0
                                           : mem + (size_t)node * 128 + (k0 - 128));
      }
    }

    // ---- two sequential j-half passes over the SAME A tile ----
#pragma unroll 1
    for (int jh = 0; jh < 2; ++jh) {
      // bfrag for this half: 16 coalesced 1KB wave-loads, 32 regs, resident
      const unsigned short* wb = Wc2 + (size_t)(jh * 4 + wsub) * 16384 + (size_t)lane * 8;
      ushort8v bf[8][2];
#pragma unroll
      for (int ks = 0; ks < 8; ++ks)
#pragma unroll
        for (int t = 0; t < 2; ++t)
          bf[ks][t] = *(const ushort8v*)(wb + (ks * 4 + jtb + t) * 512);

      f32x4 acc[2][4] = {};
#pragma unroll
      for (int ks = 0; ks < 8; ++ks) {
        const int kk = ks * 32 + kq;
        ushort8v a0 = *(const ushort8v*)&As[buf][lr][kk];        // nodes +0..15
        ushort8v a1 = *(const ushort8v*)&As[buf][lr + 16][kk];   // nodes +16..31
        ushort8v a2 = *(const ushort8v*)&As[buf][lr + 32][kk];   // nodes +32..47
        ushort8v a3 = *(const ushort8v*)&As[buf][lr + 48][kk];   // nodes +48..63
#pragma unroll
        for (int t = 0; t < 2; ++t) {
          acc[t][0] = __builtin_amdgcn_mfma_f32_16x16x32_bf16((short8v)bf[ks][t], (short8v)a0, acc[t][0], 0, 0, 0);
          acc[t][1] = __builtin_amdgcn_mfma_f32_16x16x32_bf16((short8v)bf[ks][t], (short8v)a1, acc[t][1], 0, 0, 0);
          acc[t][2] = __builtin_amdgcn_mfma_f32_16x16x32_bf16((short8v)bf[ks][t], (short8v)a2, acc[t][2], 0, 0, 0);
          acc[t][3] = __builtin_amdgcn_mfma_f32_16x16x32_bf16((short8v)bf[ks][t], (short8v)a3, acc[t][3], 0, 0, 0);
        }
      }

      // store this half: C row = j (4 consecutive j/lane -> 8B packed store)
#pragma unroll
      for (int t = 0; t < 2; ++t) {
        const int jq = jh * 256 + wid * 32 + t * 16 + (lane >> 4) * 4;
        float4 bv;
        if (jh == 0) bv = *(const float4*)(b1 + jq);
        else         bv = float4{0.f, 0.f, 0.f, 0.f};
#pragma unroll
        for (int h = 0; h < 4; ++h) {
          int node = tile * 64 + h * 16 + lr;
          if (node < NNODES) {
            f32x4 v = acc[t][h];
            uint2 pk { cvt_pk(v[0] + bv.x, v[1] + bv.y),
                       cvt_pk(v[2] + bv.z, v[3] + bv.w) };
            *(uint2*)(P + (size_t)node * 512 + jq) = pk;
          }
        }
      }
    }

    // write next tile into the OTHER buffer; one barrier per tile
    if (more) {
#pragma unroll
      for (int i = 0; i < 8; ++i) {
        int q = tid + i * 512;
        int row = q >> 6;
        int k0  = (q & 63) * 4;
        uint2 pk { cvt_pk(g[i].x, g[i].y), cvt_pk(g[i].z, g[i].w) };
        *(uint2*)&As[buf ^ 1][row][k0] = pk;
      }
    }
    __syncthreads();
  }
}

// ---------------------------------------------------------------------------
// Edge score v4 (proven r13/r14/r19): 4 edges/wave, 16 lanes/edge, each lane
// reads 16 bf16 at element offset l4*16 from each of the two P halves.
// out[e] = relu(P[src][0:256] + P[dst][256:512]) . W2 + b2
// ---------------------------------------------------------------------------
__global__ __launch_bounds__(256) void edge_score4(const int* __restrict__ src,
                                                   const int* __restrict__ dst,
                                                   const unsigned short* __restrict__ P,
                                                   const float* __restrict__ W2,
                                                   const float* __restrict__ b2,
                                                   float* __restrict__ out) {
  const int t  = threadIdx.x;
  const int l4 = t & 15;                     // lane within 16-group
  const int e  = blockIdx.x * 16 + (t >> 4);

  float4 w0  = *(const float4*)(W2 + l4 * 16);
  float4 w1  = *(const float4*)(W2 + l4 * 16 + 4);
  float4 w2v = *(const float4*)(W2 + l4 * 16 + 8);
  float4 w3  = *(const float4*)(W2 + l4 * 16 + 12);
  const float b2c = b2[0];

  const int s = src[e];
  const int d = dst[e];

  const unsigned short* ps = P + (size_t)s * 512 + l4 * 16;
  const unsigned short* pd = P + (size_t)d * 512 + 256 + l4 * 16;
  ushort8v a0 = *(const ushort8v*)(ps);
  ushort8v a1 = *(const ushort8v*)(ps + 8);
  ushort8v c0 = *(const ushort8v*)(pd);
  ushort8v c1 = *(const ushort8v*)(pd + 8);

  float partial = 0.f;
#pragma unroll
  for (int i = 0; i < 4; ++i) {
    float h = bf2f(a0[i]) + bf2f(c0[i]); h = h > 0.f ? h : 0.f;
    partial += h * (&w0.x)[i];
  }
#pragma unroll
  for (int i = 0; i < 4; ++i) {
    float h = bf2f(a0[i + 4]) + bf2f(c0[i + 4]); h = h > 0.f ? h : 0.f;
    partial += h * (&w1.x)[i];
  }
#pragma unroll
  for (int i = 0; i < 4; ++i) {
    float h = bf2f(a1[i]) + bf2f(c1[i]); h = h > 0.f ? h : 0.f;
    partial += h * (&w2v.x)[i];
  }
#pragma unroll
  for (int i = 0; i < 4; ++i) {
    float h = bf2f(a1[i + 4]) + bf2f(c1[i + 4]); h = h > 0.f ? h : 0.f;
    partial += h * (&w3.x)[i];
  }

#pragma unroll
  for (int off = 8; off; off >>= 1) partial += __shfl_xor(partial, off, 64);

  if (l4 == 0) out[e] = partial + b2c;
}

// ---------------------------------------------------------------------------
// Fallback (only if ws_size too small): direct per-edge MLP, 8 edges / block.
// ---------------------------------------------------------------------------
__global__ __launch_bounds__(256) void fallback_edge(const int* __restrict__ src,
                                                     const int* __restrict__ dst,
                                                     const float* __restrict__ ne,
                                                     const float* __restrict__ mem,
                                                     const float* __restrict__ W1,
                                                     const float* __restrict__ b1,
                                                     const float* __restrict__ W2,
                                                     const float* __restrict__ b2,
                                                     float* __restrict__ out) {
  __shared__ float hs[8][512];
  __shared__ float red[8][4];
  const int tid = threadIdx.x;
  const int e0  = blockIdx.x * 8;

  for (int idx = tid; idx < 8 * 512; idx += 256) {
    int e8 = idx >> 9, k = idx & 511;
    int e = e0 + e8;
    int s = src[e], d = dst[e];
    float v;
    if (k < 128)      v = ne[(size_t)s * 128 + k];
    else if (k < 256) v = ne[(size_t)d * 128 + k - 128];
    else if (k < 384) v = mem[(size_t)s * 128 + k - 256];
    else              v = mem[(size_t)d * 128 + k - 384];
    hs[e8][k] = v;
  }
  __syncthreads();

  const int j = tid;
  float acc[8] = {0, 0, 0, 0, 0, 0, 0, 0};
  const float* w1r = W1 + (size_t)j * 512;
  for (int k = 0; k < 512; k += 4) {
    float4 w = *(const float4*)(w1r + k);
#pragma unroll
    for (int e8 = 0; e8 < 8; ++e8)
      acc[e8] += hs[e8][k] * w.x + hs[e8][k + 1] * w.y + hs[e8][k + 2] * w.z + hs[e8][k + 3] * w.w;
  }
  const float bj = b1[j], wj = W2[j];
#pragma unroll
  for (int e8 = 0; e8 < 8; ++e8) {
    float h = acc[e8] + bj;
    h = h > 0.f ? h : 0.f;
    acc[e8] = h * wj;
  }
  const int lane = tid & 63, wid = tid >> 6;
#pragma unroll
  for (int e8 = 0; e8 < 8; ++e8) {
    float p = acc[e8];
#pragma unroll
    for (int off = 32; off; off >>= 1) p += __shfl_xor(p, off, 64);
    if (lane == 0) red[e8][wid] = p;
  }
  __syncthreads();
  if (tid < 8) out[e0 + tid] = red[tid][0] + red[tid][1] + red[tid][2] + red[tid][3] + b2[0];
}

// ---------------------------------------------------------------------------
extern "C" void kernel_launch(void* const* d_in, const int* in_sizes, int n_in,
                              void* d_out, int out_size, void* d_ws, size_t ws_size,
                              hipStream_t stream) {
  const int*   src      = (const int*)d_in[0];
  const int*   dst      = (const int*)d_in[1];
  const float* node_emb = (const float*)d_in[4];
  const float* memv     = (const float*)d_in[5];
  const float* W1       = (const float*)d_in[10];
  const float* b1       = (const float*)d_in[11];
  const float* W2       = (const float*)d_in[12];
  const float* b2       = (const float*)d_in[13];
  float*       out      = (float*)d_out;

  const size_t P_BYTES  = (size_t)NNODES * 512 * 2;   // 102,400,000
  const size_t WC_BYTES = (size_t)512 * 256 * 2;      //     262,144

  if (ws_size >= P_BYTES + WC_BYTES) {
    unsigned short* P   = (unsigned short*)d_ws;
    unsigned short* Wc2 = (unsigned short*)((char*)d_ws + P_BYTES);
    prep_wc2<<<512, 256, 0, stream>>>(W1, Wc2);
    gemm_proj21<<<GEMM_BLOCKS, 512, 0, stream>>>(node_emb, memv, Wc2, b1, P);
    edge_score4<<<EDGES / 16, 256, 0, stream>>>(src, dst, P, W2, b2, out);
  } else {
    fallback_edge<<<EDGES / 8, 256, 0, stream>>>(src, dst, node_emb, memv, W1, b1, W2, b2, out);
  }
}

// Round 22
// 90.398 us; speedup vs baseline: 1.3193x; 1.3193x over previous
//
#include <hip/hip_runtime.h>

#define NNODES 100000
#define EDGES  262144
#define NTILES 3125          // NNODES / 32
#define GEMM_BLOCKS 256      // champion config (r19): 1 block/CU, 13 iters/block

typedef __attribute__((ext_vector_type(8))) short short8v;
typedef __attribute__((ext_vector_type(8))) unsigned short ushort8v;
typedef __attribute__((ext_vector_type(4))) float f32x4;

__device__ __forceinline__ unsigned short f2bf(float f) {
  unsigned u = __builtin_bit_cast(unsigned, f);
  u += 0x7fffu + ((u >> 16) & 1u);
  return (unsigned short)(u >> 16);
}
__device__ __forceinline__ float bf2f(unsigned short u) {
  return __builtin_bit_cast(float, (unsigned)u << 16);
}
// HW packed f32->bf16 (RNE), two values -> one dword [lo|hi]
__device__ __forceinline__ unsigned cvt_pk(float lo, float hi) {
  unsigned r;
  asm volatile("v_cvt_pk_bf16_f32 %0, %1, %2" : "=v"(r) : "v"(lo), "v"(hi));
  return r;
}

// ---------------------------------------------------------------------------
// Kernel 0: repack W1 (fp32 [256][512]) -> Wc2 in WAVE-FRAGMENT order:
// Wc2[wid][ks][jt][lane][8] ushorts (256 KB).  A wave's bfrag[ks][jt] remat
// load is ONE contiguous 1 KB wave-load (proven r19: gemm ~55 -> ~50 us).
// Element: j = wid*64 + jt*16 + (lane&15); k = ks*32 + (lane>>4)*8 + m;
// value  = W1[j&255][k + (k>=128?128:0) + (j>=256?128:0)].
// ---------------------------------------------------------------------------
__global__ __launch_bounds__(256) void prep_wc2(const float* __restrict__ W1,
                                                unsigned short* __restrict__ Wc2) {
  int idx  = blockIdx.x * 256 + threadIdx.x;   // 0 .. 131071
  int m    = idx & 7;
  int lane = (idx >> 3) & 63;
  int jt   = (idx >> 9) & 3;
  int ks   = (idx >> 11) & 7;
  int wid  = idx >> 14;                        // 0..7
  int j = wid * 64 + jt * 16 + (lane & 15);
  int k = ks * 32 + (lane >> 4) * 8 + m;
  int jj = j & 255;
  int kk = k + (k >= 128 ? 128 : 0) + (j >= 256 ? 128 : 0);
  Wc2[idx] = f2bf(W1[jj * 512 + kk]);
}

// ---------------------------------------------------------------------------
// GEMM champion (r19): 512 thr = 8 waves; wave owns 64 j; 32-node tiles.
// bfrag[8][4] sourced from Wc2 by coalesced 1KB wave-loads -> compiler
// REMATERIALIZES from L2 at the 512-thr 128-VGPR budget (no spill).
// Local optimum verified against: 2 blocks/CU (r11/r20), 64-node tiles
// (r13/r15/r21), j-split grid (r17), two-pass (r16), async-LDS (r18).
//
// P[n][j] = sum_k h[n][k]*Wc[j][k] + (j<256 ? b1[j] : 0)
// Swapped-operand MFMA: C row = j, col = node -> packed uint2 stores.
// ---------------------------------------------------------------------------
__global__ __launch_bounds__(512)
void gemm_proj19(const float* __restrict__ ne,
                 const float* __restrict__ mem,
                 const unsigned short* __restrict__ Wc2,
                 const float* __restrict__ b1,
                 unsigned short* __restrict__ P) {
  __shared__ __align__(16) unsigned short As[2][32][272];  // stride 272: 0 conflicts
  const int tid  = threadIdx.x;
  const int bid  = blockIdx.x;
  const int wid  = tid >> 6;          // 0..7
  const int lane = tid & 63;
  const int lr   = lane & 15;
  const int kq   = (lane >> 4) * 8;   // 0,8,16,24
  const int cb   = wid * 64;          // this wave's j base

  // ---- B panel: coalesced 16B/lane loads from Wc2 -> remat-able ----
  const unsigned short* wbase = Wc2 + ((size_t)wid * 8 * 4 * 64 + (size_t)lane) * 8;
  ushort8v bfrag[8][4];
#pragma unroll
  for (int ks = 0; ks < 8; ++ks)
#pragma unroll
    for (int jt = 0; jt < 4; ++jt)
      bfrag[ks][jt] = *(const ushort8v*)(wbase + ((size_t)ks * 4 + jt) * 64 * 8);

  const int nt = (NTILES - bid + GEMM_BLOCKS - 1) / GEMM_BLOCKS;

  // ---- stage tile 0 (2048 float4-chunks / 512 thr -> g[4]) ----
  float4 g[4];
#pragma unroll
  for (int i = 0; i < 4; ++i) {
    int q = tid + i * 512;            // 0..2047
    int row = q >> 6;
    int k0  = (q & 63) * 4;
    int node = bid * 32 + row;
    g[i] = *(const float4*)((k0 < 128) ? ne + (size_t)node * 128 + k0
                                       : mem + (size_t)node * 128 + (k0 - 128));
  }
#pragma unroll
  for (int i = 0; i < 4; ++i) {
    int q = tid + i * 512;
    int row = q >> 6;
    int k0  = (q & 63) * 4;
    uint2 pk { cvt_pk(g[i].x, g[i].y), cvt_pk(g[i].z, g[i].w) };
    *(uint2*)&As[0][row][k0] = pk;
  }
  __syncthreads();

  for (int it = 0; it < nt; ++it) {
    const int tile = bid + it * GEMM_BLOCKS;
    const int buf  = it & 1;
    const bool more = (it + 1 < nt);

    // issue next tile's global loads EARLY (hide HBM latency under MFMA)
    if (more) {
      const int ntile = bid + (it + 1) * GEMM_BLOCKS;
#pragma unroll
      for (int i = 0; i < 4; ++i) {
        int q = tid + i * 512;
        int row = q >> 6;
        int k0  = (q & 63) * 4;
        int node = ntile * 32 + row;
        g[i] = *(const float4*)((k0 < 128) ? ne + (size_t)node * 128 + k0
                                           : mem + (size_t)node * 128 + (k0 - 128));
      }
    }

    // ---- MFMA over K=256 (swapped: A=W-frag, B=node-frag), fully unrolled ----
    f32x4 acc[4][2] = {};
#pragma unroll
    for (int ks = 0; ks < 8; ++ks) {
      const int kk = ks * 32 + kq;
      ushort8v a0 = *(const ushort8v*)&As[buf][lr][kk];        // nodes 0..15
      ushort8v a1 = *(const ushort8v*)&As[buf][lr + 16][kk];   // nodes 16..31
#pragma unroll
      for (int jt = 0; jt < 4; ++jt) {
        acc[jt][0] = __builtin_amdgcn_mfma_f32_16x16x32_bf16((short8v)bfrag[ks][jt], (short8v)a0, acc[jt][0], 0, 0, 0);
        acc[jt][1] = __builtin_amdgcn_mfma_f32_16x16x32_bf16((short8v)bfrag[ks][jt], (short8v)a1, acc[jt][1], 0, 0, 0);
      }
    }

    // ---- store: C row = j (4 consecutive per lane -> one 8B packed store) ----
#pragma unroll
    for (int jt = 0; jt < 4; ++jt) {
      const int jq = cb + jt * 16 + (lane >> 4) * 4;     // lane's 4-j base
      float4 bv = (cb < 256) ? *(const float4*)(b1 + jq) : float4{0.f, 0.f, 0.f, 0.f};
#pragma unroll
      for (int h = 0; h < 2; ++h) {
        int node = tile * 32 + h * 16 + lr;
        f32x4 v = acc[jt][h];
        uint2 pk { cvt_pk(v[0] + bv.x, v[1] + bv.y),
                   cvt_pk(v[2] + bv.z, v[3] + bv.w) };
        *(uint2*)(P + (size_t)node * 512 + jq) = pk;
      }
    }

    // write next tile into the OTHER buffer; one barrier per tile
    if (more) {
#pragma unroll
      for (int i = 0; i < 4; ++i) {
        int q = tid + i * 512;
        int row = q >> 6;
        int k0  = (q & 63) * 4;
        uint2 pk { cvt_pk(g[i].x, g[i].y), cvt_pk(g[i].z, g[i].w) };
        *(uint2*)&As[buf ^ 1][row][k0] = pk;
      }
    }
    __syncthreads();
  }
}

// ---------------------------------------------------------------------------
// Edge score v4 (proven r13/r14/r19): 4 edges/wave, 16 lanes/edge, each lane
// reads 16 bf16 at element offset l4*16 from each of the two P halves.
// out[e] = relu(P[src][0:256] + P[dst][256:512]) . W2 + b2
// ---------------------------------------------------------------------------
__global__ __launch_bounds__(256) void edge_score4(const int* __restrict__ src,
                                                   const int* __restrict__ dst,
                                                   const unsigned short* __restrict__ P,
                                                   const float* __restrict__ W2,
                                                   const float* __restrict__ b2,
                                                   float* __restrict__ out) {
  const int t  = threadIdx.x;
  const int l4 = t & 15;                     // lane within 16-group
  const int e  = blockIdx.x * 16 + (t >> 4);

  float4 w0  = *(const float4*)(W2 + l4 * 16);
  float4 w1  = *(const float4*)(W2 + l4 * 16 + 4);
  float4 w2v = *(const float4*)(W2 + l4 * 16 + 8);
  float4 w3  = *(const float4*)(W2 + l4 * 16 + 12);
  const float b2c = b2[0];

  const int s = src[e];
  const int d = dst[e];

  const unsigned short* ps = P + (size_t)s * 512 + l4 * 16;
  const unsigned short* pd = P + (size_t)d * 512 + 256 + l4 * 16;
  ushort8v a0 = *(const ushort8v*)(ps);
  ushort8v a1 = *(const ushort8v*)(ps + 8);
  ushort8v c0 = *(const ushort8v*)(pd);
  ushort8v c1 = *(const ushort8v*)(pd + 8);

  float partial = 0.f;
#pragma unroll
  for (int i = 0; i < 4; ++i) {
    float h = bf2f(a0[i]) + bf2f(c0[i]); h = h > 0.f ? h : 0.f;
    partial += h * (&w0.x)[i];
  }
#pragma unroll
  for (int i = 0; i < 4; ++i) {
    float h = bf2f(a0[i + 4]) + bf2f(c0[i + 4]); h = h > 0.f ? h : 0.f;
    partial += h * (&w1.x)[i];
  }
#pragma unroll
  for (int i = 0; i < 4; ++i) {
    float h = bf2f(a1[i]) + bf2f(c1[i]); h = h > 0.f ? h : 0.f;
    partial += h * (&w2v.x)[i];
  }
#pragma unroll
  for (int i = 0; i < 4; ++i) {
    float h = bf2f(a1[i + 4]) + bf2f(c1[i + 4]); h = h > 0.f ? h : 0.f;
    partial += h * (&w3.x)[i];
  }

#pragma unroll
  for (int off = 8; off; off >>= 1) partial += __shfl_xor(partial, off, 64);

  if (l4 == 0) out[e] = partial + b2c;
}

// ---------------------------------------------------------------------------
// Fallback (only if ws_size too small): direct per-edge MLP, 8 edges / block.
// ---------------------------------------------------------------------------
__global__ __launch_bounds__(256) void fallback_edge(const int* __restrict__ src,
                                                     const int* __restrict__ dst,
                                                     const float* __restrict__ ne,
                                                     const float* __restrict__ mem,
                                                     const float* __restrict__ W1,
                                                     const float* __restrict__ b1,
                                                     const float* __restrict__ W2,
                                                     const float* __restrict__ b2,
                                                     float* __restrict__ out) {
  __shared__ float hs[8][512];
  __shared__ float red[8][4];
  const int tid = threadIdx.x;
  const int e0  = blockIdx.x * 8;

  for (int idx = tid; idx < 8 * 512; idx += 256) {
    int e8 = idx >> 9, k = idx & 511;
    int e = e0 + e8;
    int s = src[e], d = dst[e];
    float v;
    if (k < 128)      v = ne[(size_t)s * 128 + k];
    else if (k < 256) v = ne[(size_t)d * 128 + k - 128];
    else if (k < 384) v = mem[(size_t)s * 128 + k - 256];
    else              v = mem[(size_t)d * 128 + k - 384];
    hs[e8][k] = v;
  }
  __syncthreads();

  const int j = tid;
  float acc[8] = {0, 0, 0, 0, 0, 0, 0, 0};
  const float* w1r = W1 + (size_t)j * 512;
  for (int k = 0; k < 512; k += 4) {
    float4 w = *(const float4*)(w1r + k);
#pragma unroll
    for (int e8 = 0; e8 < 8; ++e8)
      acc[e8] += hs[e8][k] * w.x + hs[e8][k + 1] * w.y + hs[e8][k + 2] * w.z + hs[e8][k + 3] * w.w;
  }
  const float bj = b1[j], wj = W2[j];
#pragma unroll
  for (int e8 = 0; e8 < 8; ++e8) {
    float h = acc[e8] + bj;
    h = h > 0.f ? h : 0.f;
    acc[e8] = h * wj;
  }
  const int lane = tid & 63, wid = tid >> 6;
#pragma unroll
  for (int e8 = 0; e8 < 8; ++e8) {
    float p = acc[e8];
#pragma unroll
    for (int off = 32; off; off >>= 1) p += __shfl_xor(p, off, 64);
    if (lane == 0) red[e8][wid] = p;
  }
  __syncthreads();
  if (tid < 8) out[e0 + tid] = red[tid][0] + red[tid][1] + red[tid][2] + red[tid][3] + b2[0];
}

// ---------------------------------------------------------------------------
extern "C" void kernel_launch(void* const* d_in, const int* in_sizes, int n_in,
                              void* d_out, int out_size, void* d_ws, size_t ws_size,
                              hipStream_t stream) {
  const int*   src      = (const int*)d_in[0];
  const int*   dst      = (const int*)d_in[1];
  const float* node_emb = (const float*)d_in[4];
  const float* memv     = (const float*)d_in[5];
  const float* W1       = (const float*)d_in[10];
  const float* b1       = (const float*)d_in[11];
  const float* W2       = (const float*)d_in[12];
  const float* b2       = (const float*)d_in[13];
  float*       out      = (float*)d_out;

  const size_t P_BYTES  = (size_t)NNODES * 512 * 2;   // 102,400,000
  const size_t WC_BYTES = (size_t)512 * 256 * 2;      //     262,144

  if (ws_size >= P_BYTES + WC_BYTES) {
    unsigned short* P   = (unsigned short*)d_ws;
    unsigned short* Wc2 = (unsigned short*)((char*)d_ws + P_BYTES);
    prep_wc2<<<512, 256, 0, stream>>>(W1, Wc2);
    gemm_proj19<<<GEMM_BLOCKS, 512, 0, stream>>>(node_emb, memv, Wc2, b1, P);
    edge_score4<<<EDGES / 16, 256, 0, stream>>>(src, dst, P, W2, b2, out);
  } else {
    fallback_edge<<<EDGES / 8, 256, 0, stream>>>(src, dst, node_emb, memv, W1, b1, W2, b2, out);
  }
}